// Round 6
// baseline (476.207 us; speedup 1.0000x reference)
//
#include <hip/hip_runtime.h>
#include <hip/hip_bf16.h>
#include <math.h>

#define SEQ_LEN 128
#define BATCH   32
#define T       32
#define TT      (T*T)     // 1024
#define TTT     (T*T*T)   // 32768
#define START   30
#define END     31
#define NPAIR   63

#define LOG2E   1.44269504088896f
#define OFF4    5.77078016355587f   // 4 * log2(e)

typedef unsigned int u32;

// tag = low 7 mantissa bits of the published f32 (self-consistent word)
__device__ __forceinline__ u32 ald32(const u32* p) {
    return __hip_atomic_load(p, __ATOMIC_RELAXED, __HIP_MEMORY_SCOPE_AGENT);
}
__device__ __forceinline__ void ast32(u32* p, u32 v) {
    __hip_atomic_store(p, v, __ATOMIC_RELAXED, __HIP_MEMORY_SCOPE_AGENT);
}
__device__ __forceinline__ float clrtag(u32 x) {
    union { u32 u; float f; } c; c.u = x & ~127u; return c.f;
}
__device__ __forceinline__ u32 mktag(float v, u32 tag) {
    union { float f; u32 u; } c; c.f = v; return (c.u & ~127u) | tag;
}

// raw barrier: drain LDS ops only; global loads stay in flight
#define BLOCK_SYNC() do {                                   \
    asm volatile("s_waitcnt lgkmcnt(0)" ::: "memory");      \
    __builtin_amdgcn_sched_barrier(0);                      \
    __builtin_amdgcn_s_barrier();                           \
    __builtin_amdgcn_sched_barrier(0);                      \
} while (0)

// ---------------------------------------------------------------------------
// Kernel 1: tg_energy gather. ws[0..15] <- per-block partial sums.
// ---------------------------------------------------------------------------
__global__ __launch_bounds__(256) void tg_kernel(const float* __restrict__ scores,
                                                 const int*   __restrict__ target,
                                                 const int*   __restrict__ mask,
                                                 float*       __restrict__ ws) {
    int idx = blockIdx.x * 256 + threadIdx.x;
    float v = 0.0f;
    if (mask[idx] != 0) v = scores[(size_t)idx * TTT + target[idx]];
    #pragma unroll
    for (int off = 32; off > 0; off >>= 1) v += __shfl_down(v, off, 64);
    __shared__ float partial[4];
    int wave = threadIdx.x >> 6, lane = threadIdx.x & 63;
    if (lane == 0) partial[wave] = v;
    __syncthreads();
    if (threadIdx.x == 0)
        ws[blockIdx.x] = partial[0] + partial[1] + partial[2] + partial[3];
}

// ---------------------------------------------------------------------------
// Kernel 2: init. Clears all pub tags (poison=0xAA has tag 42!), then writes
// Q_1 = exp(p1+s1) into slot (parity1, pub0) with tag 127.
// Slot layout: word W = chunk(c>>2)*128 + r*4 + (c&3) holds M[r][c].
// ---------------------------------------------------------------------------
__global__ __launch_bounds__(256) void init_pair(const float* __restrict__ scores,
                                                 u32* __restrict__ pub) {
    int b = blockIdx.x, tid = threadIdx.x;
    u32* myb = pub + (size_t)b * 2 * 8 * 1024;
    #pragma unroll
    for (int q = 0; q < 64; ++q) myb[q * 256 + tid] = 0u;   // clear 16 slots
    __syncthreads();
    #pragma unroll
    for (int q = 0; q < 4; ++q) {
        int W = tid * 4 + q;
        int r = (W >> 2) & 31, c = (W >> 7) * 4 + (W & 3);
        float p1 = scores[(size_t)(0*BATCH + b)*TTT + START*TT + START*T + r];
        float s1 = scores[(size_t)(1*BATCH + b)*TTT + START*TT + r*T + c];
        myb[8 * 1024 + W] = mktag(__expf(p1 + s1), 127u);
    }
}

// ---------------------------------------------------------------------------
// Kernel 3: fused-pair distributed scan. 256 blocks = 32 batch x 8 groups,
// 320 threads = wave0 (gather/spin) + 4 compute waves (256 threads).
// Pair p = steps (2+2p, 3+2p). Block g owns j-chunk jc=[4g,4g+4).
//   phase1: I[j',k]   = sum_i  Q[i,j0+j'] * exp(s_t0[i,j0+j',k]-4)   (contig 512B runs)
//   phase2: P_g[k,l]  = sum_j' I[j',k]    * exp(s_t1[j0+j',k,l]-4)   (contig 16KB)
// Publish P_g tagged (p+1) into buf[p&1]; readers sum 8 partials (their
// 128-word column-chunk only). No fences anywhere; all words self-tagged.
// ---------------------------------------------------------------------------
__global__ __launch_bounds__(320) void scan_pair(const float* __restrict__ scores,
                                                 const int*   __restrict__ maskI,
                                                 u32*         __restrict__ pub) {
    const int bid  = blockIdx.x;
    const int b    = bid & (BATCH - 1);
    const int g    = bid >> 5;
    const int tid  = threadIdx.x;
    const int lane = tid & 63;
    const bool w0  = (tid < 64);
    const int ct   = w0 ? 0 : (tid - 64);   // compute-thread index 0..255
    const int j0   = 4 * g;

    __shared__ float Qcol[128];   // Qcol[c'*32 + r] = Q[r, j0+c']
    __shared__ float Ild[128];    // I[j'*32 + k]
    __shared__ int   lmask[SEQ_LEN];

    if (tid < SEQ_LEN) lmask[tid] = maskI[tid * BATCH + b];
    __syncthreads();

    u32* const myb = pub + (size_t)b * 2 * 8 * 1024;

    auto modeOf = [&](int p) -> int {
        int a0 = lmask[2 + 2*p], a1 = lmask[3 + 2*p];
        return (a0 && a1) ? 2 : ((a0 | a1) ? 1 : 0);
    };
    auto actT = [&](int p) -> int { return lmask[2 + 2*p] ? (2 + 2*p) : (3 + 2*p); };

    // compute-thread geometry
    const int jp1 = ct >> 6;          // phase1 j' (0..3) == wave-1 index
    const int k1  = (ct >> 1) & 31;   // phase1 k
    const int h1  = ct & 1;           // phase1 i-half
    const int k2  = ct >> 3;          // phase2 k (0..31)
    const int l4  = ct & 7;           // phase2 l-quad

    float  e0[16];
    float4 e1[4];

    auto issueE0 = [&](int t) {   // E slice [i][j0+jp1][k1], i in [16h1,16h1+16)
        const float* base = scores + ((size_t)t*BATCH + b)*TTT + (size_t)(j0 + jp1)*T + k1;
        #pragma unroll
        for (int m = 0; m < 16; ++m) e0[m] = base[(size_t)(16*h1 + m) * TT];
    };
    auto issueE1 = [&](int t) {   // E slice [j0+j'][k2][4*l4 ..]
        const float* base = scores + ((size_t)t*BATCH + b)*TTT + (size_t)k2*T + l4*4;
        #pragma unroll
        for (int jj = 0; jj < 4; ++jj) e1[jj] = *(const float4*)(base + (size_t)(j0 + jj)*TT);
    };

    // prologue prefetch for pair 0
    if (!w0) {
        int m0 = modeOf(0);
        if (m0 == 2)      { issueE0(2); issueE1(3); }
        else if (m0 == 1) { issueE0(actT(0)); }
    }

    // previous-publish tracker (uniform across all blocks of batch)
    int ptag = 127, ppar = 1, pmode = 3;   // 3 = init (single pub, full matrix)

    for (int p = 0; p < NPAIR; ++p) {
        const int md = modeOf(p);

        // ------------- wave0: gather input Q columns -------------
        if (w0 && md != 0) {
            if (pmode == 3) {            // init: pub0 full chunk
                const u32* s0 = myb + (ppar*8 + 0)*1024 + g*128;
                u32 x;
                do { x = ald32(s0 + lane); } while ((x & 127u) != (u32)ptag);
                float v0 = clrtag(x);
                do { x = ald32(s0 + 64 + lane); } while ((x & 127u) != (u32)ptag);
                float v1 = clrtag(x);
                Qcol[(lane & 3)*32 + (lane >> 2)]           = v0;
                Qcol[((lane+64) & 3)*32 + ((lane+64) >> 2)] = v1;
            } else if (pmode == 2) {     // fused: sum 8 partial chunks
                float a0s = 0.f, a1s = 0.f;
                #pragma unroll
                for (int hh = 0; hh < 8; ++hh) {
                    const u32* s0 = myb + (ppar*8 + hh)*1024 + g*128;
                    u32 x;
                    do { x = ald32(s0 + lane); } while ((x & 127u) != (u32)ptag);
                    a0s += clrtag(x);
                    do { x = ald32(s0 + 64 + lane); } while ((x & 127u) != (u32)ptag);
                    a1s += clrtag(x);
                }
                Qcol[(lane & 3)*32 + (lane >> 2)]           = a0s;
                Qcol[((lane+64) & 3)*32 + ((lane+64) >> 2)] = a1s;
            } else {                     // single: rows 4h..4h+3 from pub h
                if (lane < 32) {
                    const int hh = lane >> 2, r = 4*hh + (lane & 3);
                    const u32* s0 = myb + (ppar*8 + hh)*1024 + g*128 + r*4;
                    #pragma unroll
                    for (int c = 0; c < 4; ++c) {
                        u32 x;
                        do { x = ald32(s0 + c); } while ((x & 127u) != (u32)ptag);
                        Qcol[c*32 + r] = clrtag(x);
                    }
                }
            }
        }
        BLOCK_SYNC();   // B1: Qcol ready

        // ------------- compute: phase1 (or full single step) -------------
        if (!w0 && md != 0) {
            float acc = 0.f;
            #pragma unroll
            for (int m = 0; m < 16; ++m) {
                float E = exp2f(fmaf(e0[m], LOG2E, -OFF4));
                acc = fmaf(E, Qcol[jp1*32 + 16*h1 + m], acc);
            }
            acc += __shfl_xor(acc, 1, 64);
            if (md == 2) {
                if (h1 == 0) Ild[jp1*32 + k1] = acc;
            } else {
                if (h1 == 0) {   // publish final row entry M[j0+jp1, k1]
                    u32* dst = myb + ((p & 1)*8 + g)*1024
                             + (k1 >> 2)*128 + (j0 + jp1)*4 + (k1 & 3);
                    ast32(dst, mktag(acc, (u32)(p + 1)));
                }
            }
        }
        // prefetch next pair's phase1 slice (exchange latency hides HBM)
        if (!w0 && p + 1 < NPAIR) {
            int mn = modeOf(p + 1);
            if (mn == 2)      issueE0(2 + 2*(p + 1));
            else if (mn == 1) issueE0(actT(p + 1));
        }
        BLOCK_SYNC();   // B2: I ready, Qcol consumption done

        // ------------- compute: phase2 + publish partials -------------
        if (!w0 && md == 2) {
            float ox = 0.f, oy = 0.f, oz = 0.f, ow = 0.f;
            #pragma unroll
            for (int jj = 0; jj < 4; ++jj) {
                float Iv = Ild[jj*32 + k2];
                ox = fmaf(exp2f(fmaf(e1[jj].x, LOG2E, -OFF4)), Iv, ox);
                oy = fmaf(exp2f(fmaf(e1[jj].y, LOG2E, -OFF4)), Iv, oy);
                oz = fmaf(exp2f(fmaf(e1[jj].z, LOG2E, -OFF4)), Iv, oz);
                ow = fmaf(exp2f(fmaf(e1[jj].w, LOG2E, -OFF4)), Iv, ow);
            }
            u32* dst = myb + ((p & 1)*8 + g)*1024 + l4*128 + k2*4;
            u32 tg_ = (u32)(p + 1);
            ast32(dst + 0, mktag(ox, tg_));
            ast32(dst + 1, mktag(oy, tg_));
            ast32(dst + 2, mktag(oz, tg_));
            ast32(dst + 3, mktag(ow, tg_));
        }
        if (!w0 && p + 1 < NPAIR && modeOf(p + 1) == 2) issueE1(3 + 2*(p + 1));

        if (md != 0) { ptag = p + 1; ppar = p & 1; pmode = md; }
    }
}

// ---------------------------------------------------------------------------
// Kernel 4: finalize. Reads last published Q[END,END] per batch + tg sum.
// ---------------------------------------------------------------------------
__global__ void finalize_pair(const float* __restrict__ wsf,
                              const u32*   __restrict__ pub,
                              const int*   __restrict__ mask,
                              float*       __restrict__ out) {
    __shared__ float zs[32];
    int tid = threadIdx.x;
    if (tid < 32) {
        int b = tid, cnt = 0;
        for (int t = 2; t < SEQ_LEN; ++t) cnt += (mask[t*BATCH + b] != 0);
        int lp = -1, lmode = 0;
        for (int p = NPAIR - 1; p >= 0; --p) {
            int a0 = mask[(2 + 2*p)*BATCH + b], a1 = mask[(3 + 2*p)*BATCH + b];
            int md = (a0 && a1) ? 2 : ((a0 | a1) ? 1 : 0);
            if (md) { lp = p; lmode = md; break; }
        }
        const u32* myb = pub + (size_t)b * 2 * 8 * 1024;
        float q;
        if (lp < 0)            q = clrtag(myb[8*1024 + 1023]);           // init slot
        else if (lmode == 2) { q = 0.f;
            for (int hh = 0; hh < 8; ++hh) q += clrtag(myb[((lp & 1)*8 + hh)*1024 + 1023]);
        } else                 q = clrtag(myb[((lp & 1)*8 + 7)*1024 + 1023]);
        zs[b] = 4.0f * (float)cnt + logf(q);
    }
    __syncthreads();
    if (tid == 0) {
        float tg = 0.f, z = 0.f;
        #pragma unroll
        for (int i = 0; i < 16; ++i) tg += wsf[i];
        #pragma unroll
        for (int i = 0; i < 32; ++i) z += zs[i];
        out[0] = (z - tg) / (float)BATCH;
    }
}

// ---------------------------------------------------------------------------
// Fallback (small ws): round-5 single-block-per-batch scan.
// ---------------------------------------------------------------------------
__global__ __launch_bounds__(1024) void scan_fast(const float* __restrict__ scores,
                                                  const int*   __restrict__ maskI,
                                                  float*       __restrict__ ws) {
    const int b    = blockIdx.x;
    const int tid  = threadIdx.x;
    const int w    = tid >> 6;
    const int lane = tid & 63;
    const int h    = lane >> 4;
    const int jp   = (lane >> 3) & 1;
    const int k4   = lane & 7;
    const int j    = w * 2 + jp;

    __shared__ float Q[2][TT];
    __shared__ int   lmask[SEQ_LEN];
    if (tid < SEQ_LEN) lmask[tid] = maskI[tid * BATCH + b];
    {
        int x = tid >> 5, y = tid & 31;
        float p1 = scores[(size_t)(0*BATCH + b)*TTT + START*TT + START*T + x];
        float s1 = scores[(size_t)(1*BATCH + b)*TTT + START*TT + x*T + y];
        Q[1][x*T + y] = __expf(p1 + s1);
    }
    __syncthreads();
    const int loff = h*8*TT + j*T + k4*4;
    float4 SA[8], SB[8];
    auto issue = [&](float4 (&S)[8], int t) {
        const float* p = scores + ((size_t)t*BATCH + b)*TTT + loff;
        #pragma unroll
        for (int m = 0; m < 8; ++m) S[m] = *(const float4*)(p + m*TT);
    };
    auto process = [&](float4 (&S)[8], int t) {
        const float* qc = Q[(t-1) & 1];
        float*       qn = Q[t & 1];
        #pragma unroll
        for (int m = 0; m < 8; ++m) {
            S[m].x = exp2f(fmaf(S[m].x, LOG2E, -OFF4));
            S[m].y = exp2f(fmaf(S[m].y, LOG2E, -OFF4));
            S[m].z = exp2f(fmaf(S[m].z, LOG2E, -OFF4));
            S[m].w = exp2f(fmaf(S[m].w, LOG2E, -OFF4));
        }
        float4 acc = make_float4(0.f, 0.f, 0.f, 0.f);
        #pragma unroll
        for (int m = 0; m < 8; ++m) {
            float q = qc[(h*8 + m)*T + j];
            acc.x = fmaf(S[m].x, q, acc.x);
            acc.y = fmaf(S[m].y, q, acc.y);
            acc.z = fmaf(S[m].z, q, acc.z);
            acc.w = fmaf(S[m].w, q, acc.w);
        }
        acc.x += __shfl_xor(acc.x, 16, 64); acc.y += __shfl_xor(acc.y, 16, 64);
        acc.z += __shfl_xor(acc.z, 16, 64); acc.w += __shfl_xor(acc.w, 16, 64);
        acc.x += __shfl_xor(acc.x, 32, 64); acc.y += __shfl_xor(acc.y, 32, 64);
        acc.z += __shfl_xor(acc.z, 32, 64); acc.w += __shfl_xor(acc.w, 32, 64);
        if (lane < 16) {
            if (lmask[t] != 0) *(float4*)&qn[j*T + k4*4] = acc;
            else               *(float4*)&qn[j*T + k4*4] = *(const float4*)&qc[j*T + k4*4];
        }
        BLOCK_SYNC();
    };
    issue(SA, 2);
    for (int t = 2; t < SEQ_LEN; t += 2) {
        issue(SB, t + 1);
        process(SA, t);
        if (t + 2 < SEQ_LEN) issue(SA, t + 2);
        process(SB, t + 1);
    }
    if (tid == 0) {
        int cnt = 0;
        for (int t = 2; t < SEQ_LEN; ++t) cnt += (lmask[t] != 0);
        ws[16 + b] = 4.0f * (float)cnt + logf(Q[1][END*T + END]);
    }
}

__global__ void finalize_simple(const float* __restrict__ ws, float* __restrict__ out) {
    if (threadIdx.x == 0) {
        float tg = 0.f, z = 0.f;
        #pragma unroll
        for (int i = 0; i < 16; ++i) tg += ws[i];
        #pragma unroll
        for (int i = 0; i < 32; ++i) z += ws[16 + i];
        out[0] = (z - tg) / (float)BATCH;
    }
}

extern "C" void kernel_launch(void* const* d_in, const int* in_sizes, int n_in,
                              void* d_out, int out_size, void* d_ws, size_t ws_size,
                              hipStream_t stream) {
    const float* scores = (const float*)d_in[0];
    const int*   target = (const int*)d_in[1];
    const int*   mask   = (const int*)d_in[2];
    float* out = (float*)d_out;
    float* ws  = (float*)d_ws;
    u32*   pub = (u32*)((char*)d_ws + 256);
    const size_t need = 256 + (size_t)BATCH * 2 * 8 * 1024 * sizeof(u32);   // ~2.1 MB

    tg_kernel<<<16, 256, 0, stream>>>(scores, target, mask, ws);
    if (ws_size >= need) {
        init_pair<<<BATCH, 256, 0, stream>>>(scores, pub);
        scan_pair<<<BATCH * 8, 320, 0, stream>>>(scores, mask, pub);
        finalize_pair<<<1, 64, 0, stream>>>(ws, pub, mask, out);
    } else {
        scan_fast<<<BATCH, 1024, 0, stream>>>(scores, mask, ws);
        finalize_simple<<<1, 64, 0, stream>>>(ws, out);
    }
}

// Round 7
// 243.670 us; speedup vs baseline: 1.9543x; 1.9543x over previous
//
#include <hip/hip_runtime.h>
#include <hip/hip_bf16.h>
#include <math.h>

#define SEQ_LEN 128
#define BATCH   32
#define T       32
#define TT      (T*T)     // 1024
#define TTT     (T*T*T)   // 32768
#define START   30
#define END     31
#define TMID    64        // fwd processes t=2..64, bwd t=127..65

#define LOG2E   1.44269504088896f
#define OFF4    5.77078016355587f   // 4 * log2(e)

// raw barrier: drain LDS ops only; global prefetch stays in flight
#define BLOCK_SYNC() do {                                   \
    asm volatile("s_waitcnt lgkmcnt(0)" ::: "memory");      \
    __builtin_amdgcn_sched_barrier(0);                      \
    __builtin_amdgcn_s_barrier();                           \
    __builtin_amdgcn_sched_barrier(0);                      \
} while (0)

// ---------------------------------------------------------------------------
// Kernel 1: tg_energy gather. ws[0..15] <- per-block partial sums.
// ---------------------------------------------------------------------------
__global__ __launch_bounds__(256) void tg_kernel(const float* __restrict__ scores,
                                                 const int*   __restrict__ target,
                                                 const int*   __restrict__ mask,
                                                 float*       __restrict__ ws) {
    int idx = blockIdx.x * 256 + threadIdx.x;
    float v = 0.0f;
    if (mask[idx] != 0) v = scores[(size_t)idx * TTT + target[idx]];
    #pragma unroll
    for (int off = 32; off > 0; off >>= 1) v += __shfl_down(v, off, 64);
    __shared__ float partial[4];
    int wave = threadIdx.x >> 6, lane = threadIdx.x & 63;
    if (lane == 0) partial[wave] = v;
    __syncthreads();
    if (threadIdx.x == 0)
        ws[blockIdx.x] = partial[0] + partial[1] + partial[2] + partial[3];
}

// ---------------------------------------------------------------------------
// Kernel 2: fwd/bwd scan. 64 blocks x 1024 threads.
//  block b < 32 : FORWARD  batch b, steps t=2..64.
//    Q_t[j,k] = sum_i exp(s_t[i,j,k]-4) * Q_{t-1}[i,j]; write Q_64 -> wsQ.
//  block 32+b  : BACKWARD batch b, steps t=127..65.
//    R_{t-1}[i,j] = sum_k exp(s_t[i,j,k]-4) * R_t[j,k]; write R_64 -> wsR.
//  z_b = 4*n_active + log( sum_{i,j} R_64[i,j]*Q_64[i,j] )  (finalize).
// ---------------------------------------------------------------------------
__global__ __launch_bounds__(1024) void scan_fb(const float* __restrict__ scores,
                                                const int*   __restrict__ maskI,
                                                float*       __restrict__ wsQ,
                                                float*       __restrict__ wsR) {
    const int tid  = threadIdx.x;
    const int lane = tid & 63;
    const bool fwd = (blockIdx.x < BATCH);
    const int b    = fwd ? blockIdx.x : (blockIdx.x - BATCH);

    __shared__ int lmask[SEQ_LEN];
    if (tid < SEQ_LEN) lmask[tid] = maskI[tid * BATCH + b];

    if (fwd) {
        // ------------------------- FORWARD -------------------------
        const int w  = tid >> 6;
        const int h  = lane >> 4;          // i-subrange [8h, 8h+8)
        const int jp = (lane >> 3) & 1;
        const int k4 = lane & 7;
        const int j  = w * 2 + jp;

        __shared__ float Q[2][TT];
        {
            int x = tid >> 5, y = tid & 31;
            float p1 = scores[(size_t)(0*BATCH + b)*TTT + START*TT + START*T + x];
            float s1 = scores[(size_t)(1*BATCH + b)*TTT + START*TT + x*T + y];
            Q[1][x*T + y] = __expf(p1 + s1);
        }
        __syncthreads();

        const int loff = h*8*TT + j*T + k4*4;
        float4 SA[8], SB[8];

        auto issue = [&](float4 (&S)[8], int t) {
            const float* p = scores + ((size_t)t*BATCH + b)*TTT + loff;
            #pragma unroll
            for (int m = 0; m < 8; ++m) S[m] = *(const float4*)(p + m*TT);
        };
        auto process = [&](float4 (&S)[8], int t) {
            const float* qc = Q[(t-1) & 1];
            float*       qn = Q[t & 1];
            #pragma unroll
            for (int m = 0; m < 8; ++m) {
                S[m].x = exp2f(fmaf(S[m].x, LOG2E, -OFF4));
                S[m].y = exp2f(fmaf(S[m].y, LOG2E, -OFF4));
                S[m].z = exp2f(fmaf(S[m].z, LOG2E, -OFF4));
                S[m].w = exp2f(fmaf(S[m].w, LOG2E, -OFF4));
            }
            float4 acc = make_float4(0.f, 0.f, 0.f, 0.f);
            #pragma unroll
            for (int m = 0; m < 8; ++m) {
                float q = qc[(h*8 + m)*T + j];
                acc.x = fmaf(S[m].x, q, acc.x);
                acc.y = fmaf(S[m].y, q, acc.y);
                acc.z = fmaf(S[m].z, q, acc.z);
                acc.w = fmaf(S[m].w, q, acc.w);
            }
            acc.x += __shfl_xor(acc.x, 16, 64); acc.y += __shfl_xor(acc.y, 16, 64);
            acc.z += __shfl_xor(acc.z, 16, 64); acc.w += __shfl_xor(acc.w, 16, 64);
            acc.x += __shfl_xor(acc.x, 32, 64); acc.y += __shfl_xor(acc.y, 32, 64);
            acc.z += __shfl_xor(acc.z, 32, 64); acc.w += __shfl_xor(acc.w, 32, 64);
            if (lane < 16) {
                if (lmask[t] != 0) *(float4*)&qn[j*T + k4*4] = acc;
                else               *(float4*)&qn[j*T + k4*4] = *(const float4*)&qc[j*T + k4*4];
            }
            BLOCK_SYNC();
        };

        issue(SA, 2);
        for (int t = 2; t < TMID; t += 2) {          // t = 2,4,...,62
            issue(SB, t + 1);
            process(SA, t);
            if (t + 2 <= TMID) issue(SA, t + 2);
            process(SB, t + 1);
        }
        process(SA, TMID);                            // t = 64 -> Q[0]

        wsQ[(size_t)b * TT + tid] = Q[TMID & 1][tid];
    } else {
        // ------------------------- BACKWARD -------------------------
        // thread: round r (0..7) -> output o = r*128 + (tid>>3); q = tid&7
        // reads E_t[i,j,4q..4q+4] (contiguous 1KB per wave per round)
        __shared__ float R[2][32*33];   // stride-33 rows: <=2-way LDS conflicts
        {
            int i = tid >> 5, jj = tid & 31;
            R[1][i*33 + jj] = (i == END && jj == END) ? 1.0f : 0.0f;  // R_127
        }
        __syncthreads();

        const int o8 = tid >> 3;    // 0..127
        const int q  = tid & 7;
        const int boff = o8*32 + q*4;

        float4 SA[8], SB[8];
        auto issue = [&](float4 (&S)[8], int t) {
            const float* p = scores + ((size_t)t*BATCH + b)*TTT + boff;
            #pragma unroll
            for (int r = 0; r < 8; ++r) S[r] = *(const float4*)(p + r*4096);
        };
        auto process = [&](float4 (&S)[8], int t) {
            const float* Rc = R[t & 1];
            float*       Rn = R[(t-1) & 1];
            if (lmask[t] != 0) {
                #pragma unroll
                for (int r = 0; r < 8; ++r) {
                    const int o = r*128 + o8;
                    const int i = o >> 5, j = o & 31;
                    float4 E = S[r];
                    E.x = exp2f(fmaf(E.x, LOG2E, -OFF4));
                    E.y = exp2f(fmaf(E.y, LOG2E, -OFF4));
                    E.z = exp2f(fmaf(E.z, LOG2E, -OFF4));
                    E.w = exp2f(fmaf(E.w, LOG2E, -OFF4));
                    const float* rr = &Rc[j*33 + 4*q];
                    float acc = E.x*rr[0] + E.y*rr[1] + E.z*rr[2] + E.w*rr[3];
                    acc += __shfl_xor(acc, 1, 64);
                    acc += __shfl_xor(acc, 2, 64);
                    acc += __shfl_xor(acc, 4, 64);
                    if (q == 0) Rn[i*33 + j] = acc;
                }
            } else {
                Rn[(tid>>5)*33 + (tid&31)] = Rc[(tid>>5)*33 + (tid&31)];
            }
            BLOCK_SYNC();
        };

        issue(SA, SEQ_LEN - 1);                       // t = 127
        for (int t = SEQ_LEN - 1; t > TMID + 1; t -= 2) {   // t = 127,125,...,67
            issue(SB, t - 1);
            process(SA, t);
            if (t - 2 >= TMID + 1) issue(SA, t - 2);
            process(SB, t - 1);
        }
        process(SA, TMID + 1);                        // t = 65 -> R[0]

        wsR[(size_t)b * TT + tid] = R[TMID & 1][(tid>>5)*33 + (tid&31)];
    }
}

// ---------------------------------------------------------------------------
// Kernel 3: finalize. 1 block x 1024 threads; wave w handles batches w, w+16.
// z_b = 4*cnt_b + log( dot(Q_64, R_64) ); out = (sum z - tg)/BATCH.
// ---------------------------------------------------------------------------
__global__ __launch_bounds__(1024) void finalize_fb(const float* __restrict__ ws,
                                                    const float* __restrict__ wsQ,
                                                    const float* __restrict__ wsR,
                                                    const int*   __restrict__ mask,
                                                    float*       __restrict__ out) {
    __shared__ float zs[32];
    const int w = threadIdx.x >> 6, lane = threadIdx.x & 63;
    for (int rep = 0; rep < 2; ++rep) {
        const int b = w + rep*16;
        float dot = 0.f;
        #pragma unroll
        for (int e = 0; e < 16; ++e) {
            const int s = lane + 64*e;
            dot += wsQ[(size_t)b*TT + s] * wsR[(size_t)b*TT + s];
        }
        float cnt = 0.f;
        {
            int t = 2 + lane;
            if (t < SEQ_LEN) cnt += (mask[t*BATCH + b] != 0) ? 1.f : 0.f;
            t += 64;
            if (t < SEQ_LEN) cnt += (mask[t*BATCH + b] != 0) ? 1.f : 0.f;
        }
        #pragma unroll
        for (int off = 32; off > 0; off >>= 1) {
            dot += __shfl_xor(dot, off, 64);
            cnt += __shfl_xor(cnt, off, 64);
        }
        if (lane == 0) zs[b] = 4.0f * cnt + logf(dot);
    }
    __syncthreads();
    if (threadIdx.x == 0) {
        float tg = 0.f, z = 0.f;
        #pragma unroll
        for (int i = 0; i < 16; ++i) tg += ws[i];
        #pragma unroll
        for (int i = 0; i < 32; ++i) z += zs[i];
        out[0] = (z - tg) / (float)BATCH;
    }
}

// ---------------------------------------------------------------------------
// Fallback (small ws): round-5 single-block-per-batch scan.
// ---------------------------------------------------------------------------
__global__ __launch_bounds__(1024) void scan_fast(const float* __restrict__ scores,
                                                  const int*   __restrict__ maskI,
                                                  float*       __restrict__ ws) {
    const int b    = blockIdx.x;
    const int tid  = threadIdx.x;
    const int w    = tid >> 6;
    const int lane = tid & 63;
    const int h    = lane >> 4;
    const int jp   = (lane >> 3) & 1;
    const int k4   = lane & 7;
    const int j    = w * 2 + jp;

    __shared__ float Q[2][TT];
    __shared__ int   lmask[SEQ_LEN];
    if (tid < SEQ_LEN) lmask[tid] = maskI[tid * BATCH + b];
    {
        int x = tid >> 5, y = tid & 31;
        float p1 = scores[(size_t)(0*BATCH + b)*TTT + START*TT + START*T + x];
        float s1 = scores[(size_t)(1*BATCH + b)*TTT + START*TT + x*T + y];
        Q[1][x*T + y] = __expf(p1 + s1);
    }
    __syncthreads();
    const int loff = h*8*TT + j*T + k4*4;
    float4 SA[8], SB[8];
    auto issue = [&](float4 (&S)[8], int t) {
        const float* p = scores + ((size_t)t*BATCH + b)*TTT + loff;
        #pragma unroll
        for (int m = 0; m < 8; ++m) S[m] = *(const float4*)(p + m*TT);
    };
    auto process = [&](float4 (&S)[8], int t) {
        const float* qc = Q[(t-1) & 1];
        float*       qn = Q[t & 1];
        #pragma unroll
        for (int m = 0; m < 8; ++m) {
            S[m].x = exp2f(fmaf(S[m].x, LOG2E, -OFF4));
            S[m].y = exp2f(fmaf(S[m].y, LOG2E, -OFF4));
            S[m].z = exp2f(fmaf(S[m].z, LOG2E, -OFF4));
            S[m].w = exp2f(fmaf(S[m].w, LOG2E, -OFF4));
        }
        float4 acc = make_float4(0.f, 0.f, 0.f, 0.f);
        #pragma unroll
        for (int m = 0; m < 8; ++m) {
            float q = qc[(h*8 + m)*T + j];
            acc.x = fmaf(S[m].x, q, acc.x);
            acc.y = fmaf(S[m].y, q, acc.y);
            acc.z = fmaf(S[m].z, q, acc.z);
            acc.w = fmaf(S[m].w, q, acc.w);
        }
        acc.x += __shfl_xor(acc.x, 16, 64); acc.y += __shfl_xor(acc.y, 16, 64);
        acc.z += __shfl_xor(acc.z, 16, 64); acc.w += __shfl_xor(acc.w, 16, 64);
        acc.x += __shfl_xor(acc.x, 32, 64); acc.y += __shfl_xor(acc.y, 32, 64);
        acc.z += __shfl_xor(acc.z, 32, 64); acc.w += __shfl_xor(acc.w, 32, 64);
        if (lane < 16) {
            if (lmask[t] != 0) *(float4*)&qn[j*T + k4*4] = acc;
            else               *(float4*)&qn[j*T + k4*4] = *(const float4*)&qc[j*T + k4*4];
        }
        BLOCK_SYNC();
    };
    issue(SA, 2);
    for (int t = 2; t < SEQ_LEN; t += 2) {
        issue(SB, t + 1);
        process(SA, t);
        if (t + 2 < SEQ_LEN) issue(SA, t + 2);
        process(SB, t + 1);
    }
    if (tid == 0) {
        int cnt = 0;
        for (int t = 2; t < SEQ_LEN; ++t) cnt += (lmask[t] != 0);
        ws[16 + b] = 4.0f * (float)cnt + logf(Q[1][END*T + END]);
    }
}

__global__ void finalize_simple(const float* __restrict__ ws, float* __restrict__ out) {
    if (threadIdx.x == 0) {
        float tg = 0.f, z = 0.f;
        #pragma unroll
        for (int i = 0; i < 16; ++i) tg += ws[i];
        #pragma unroll
        for (int i = 0; i < 32; ++i) z += ws[16 + i];
        out[0] = (z - tg) / (float)BATCH;
    }
}

extern "C" void kernel_launch(void* const* d_in, const int* in_sizes, int n_in,
                              void* d_out, int out_size, void* d_ws, size_t ws_size,
                              hipStream_t stream) {
    const float* scores = (const float*)d_in[0];
    const int*   target = (const int*)d_in[1];
    const int*   mask   = (const int*)d_in[2];
    float* out = (float*)d_out;
    float* ws  = (float*)d_ws;
    float* wsQ = ws + 1024;
    float* wsR = ws + 1024 + BATCH*TT;
    const size_t need = (1024 + 2*(size_t)BATCH*TT) * sizeof(float);   // ~266 KB

    tg_kernel<<<16, 256, 0, stream>>>(scores, target, mask, ws);
    if (ws_size >= need) {
        scan_fb<<<2*BATCH, 1024, 0, stream>>>(scores, mask, wsQ, wsR);
        finalize_fb<<<1, 1024, 0, stream>>>(ws, wsQ, wsR, mask, out);
    } else {
        scan_fast<<<BATCH, 1024, 0, stream>>>(scores, mask, ws);
        finalize_simple<<<1, 64, 0, stream>>>(ws, out);
    }
}

// Round 8
// 187.651 us; speedup vs baseline: 2.5377x; 1.2985x over previous
//
#include <hip/hip_runtime.h>
#include <hip/hip_bf16.h>
#include <math.h>

#define SEQ_LEN 128
#define BATCH   32
#define T       32
#define TT      (T*T)     // 1024
#define TTT     (T*T*T)   // 32768
#define START   30
#define END     31

#define LOG2E   1.44269504088896f
#define OFF4    5.77078016355587f   // 4 * log2(e)

typedef unsigned long long u64;

// ---- packed (tag, value): one 64-bit word is self-consistent ----
__device__ __forceinline__ u64 pt_pack(int tag, float v) {
    union { float f; unsigned int u; } c; c.f = v;
    return ((u64)(unsigned int)tag << 32) | (u64)c.u;
}
__device__ __forceinline__ float pt_val(u64 w) {
    union { unsigned int u; float f; } c; c.u = (unsigned int)w; return c.f;
}
__device__ __forceinline__ int pt_tag(u64 w) { return (int)(w >> 32); }

__device__ __forceinline__ u64 ald64(const u64* p) {
    return __hip_atomic_load(p, __ATOMIC_RELAXED, __HIP_MEMORY_SCOPE_AGENT);
}
__device__ __forceinline__ void ast64(u64* p, u64 v) {
    __hip_atomic_store(p, v, __ATOMIC_RELAXED, __HIP_MEMORY_SCOPE_AGENT);
}

// raw barrier: drain LDS ops only; global prefetch stays in flight
#define BLOCK_SYNC() do {                                   \
    asm volatile("s_waitcnt lgkmcnt(0)" ::: "memory");      \
    __builtin_amdgcn_sched_barrier(0);                      \
    __builtin_amdgcn_s_barrier();                           \
    __builtin_amdgcn_sched_barrier(0);                      \
} while (0)

// ---------------------------------------------------------------------------
// Kernel 1: tg_energy gather. ws[0..15] <- per-block partial sums.
// ---------------------------------------------------------------------------
__global__ __launch_bounds__(256) void tg_kernel(const float* __restrict__ scores,
                                                 const int*   __restrict__ target,
                                                 const int*   __restrict__ mask,
                                                 float*       __restrict__ ws) {
    int idx = blockIdx.x * 256 + threadIdx.x;
    float v = 0.0f;
    if (mask[idx] != 0) v = scores[(size_t)idx * TTT + target[idx]];
    #pragma unroll
    for (int off = 32; off > 0; off >>= 1) v += __shfl_down(v, off, 64);
    __shared__ float partial[4];
    int wave = threadIdx.x >> 6, lane = threadIdx.x & 63;
    if (lane == 0) partial[wave] = v;
    __syncthreads();
    if (threadIdx.x == 0)
        ws[blockIdx.x] = partial[0] + partial[1] + partial[2] + partial[3];
}

// ---------------------------------------------------------------------------
// Kernel 2: init tagged buffers (full overwrite each launch: replay-safe).
// Forward buffer ptF[b]: layout [second*32 + first]; parity1 <- Q_1 (tag 1),
// parity0 <- 0. Backward buffer ptB[b]: layout [first*32 + second];
// parity0 <- R_127 (tag 128, indicator at END,END), parity1 <- 0.
// ---------------------------------------------------------------------------
__global__ __launch_bounds__(256) void init_dfb(const float* __restrict__ scores,
                                                u64* __restrict__ ptF,
                                                u64* __restrict__ ptB) {
    const int blk = blockIdx.x, tid = threadIdx.x;
    if (blk < BATCH) {
        const int b = blk;
        u64* pt = ptF + (size_t)b * 2048;
        #pragma unroll
        for (int q = 0; q < 4; ++q) {
            int e = q * 256 + tid;           // e = j*32 + i
            int i = e & 31, j = e >> 5;
            float p1 = scores[(size_t)(0*BATCH + b)*TTT + START*TT + START*T + i];
            float s1 = scores[(size_t)(1*BATCH + b)*TTT + START*TT + i*T + j];
            pt[1024 + e] = pt_pack(1, __expf(p1 + s1));
            pt[e]        = 0ULL;
        }
    } else {
        const int b = blk - BATCH;
        u64* pt = ptB + (size_t)b * 2048;
        #pragma unroll
        for (int q = 0; q < 4; ++q) {
            int e = q * 256 + tid;           // e = j*32 + k
            float v = (e == END*T + END) ? 1.0f : 0.0f;
            pt[e]        = pt_pack(128, v);
            pt[1024 + e] = 0ULL;
        }
    }
}

// ---------------------------------------------------------------------------
// Kernel 3: distributed fwd/bwd scan. 512 blocks x 512 threads (2 blocks/CU,
// co-resident by construction). bid: g = bid&7, chain = bid>>3, b = chain&31,
// dirB = chain>=32. Both dirs: block owns middle-index chunk j in [4g,4g+4);
// tile s_t[i, 4g+jj, k] loaded as contiguous 512B runs, 2 float4/thread.
//  FWD (t=2..64):   Q_t[j,k]   = sum_i E[i,j,k] * Q_{t-1}[i,j]
//  BWD (t=127..65): R_{t-1}[i,j] = sum_k E[i,j,k] * R_t[j,k]
// E = exp2(s*log2e - 4*log2e). Exchange: r2's tagged-u64 relaxed protocol.
// ---------------------------------------------------------------------------
__global__ __launch_bounds__(512, 4) void scan_dfb(const float* __restrict__ scores,
                                                   const int*   __restrict__ maskI,
                                                   u64*         __restrict__ ptF,
                                                   u64*         __restrict__ ptB) {
    const int bid   = blockIdx.x;
    const int g     = bid & 7;
    const int chain = bid >> 3;
    const int b     = chain & 31;
    const bool dirB = (chain >> 5) != 0;
    const int tid   = threadIdx.x;
    const int lane  = tid & 63;

    __shared__ float smem[128 * 33];   // fwd transpose tile
    __shared__ float pld[128];         // polled prev-state chunk
    __shared__ float res[128];         // step outputs
    __shared__ int   lmask[SEQ_LEN];

    if (tid < SEQ_LEN) lmask[tid] = maskI[tid * BATCH + b];
    __syncthreads();

    u64* const pt = (dirB ? ptB : ptF) + (size_t)b * 2048;

    const int i0 = tid >> 5;                 // 0..15 (second element: i0+16)
    const int f  = tid & 31;
    const size_t offA = (size_t)i0 * TT + g * 128 + f * 4;

    // bwd geometry
    const int jjB = (tid & 31) >> 3;
    const int k4  = tid & 7;
    // fwd reduce geometry
    const int oF  = tid >> 2;                // output jj*32+k
    const int s4  = tid & 3;
    const int jjF = oF >> 5;

    float4 SA0, SA1, SB0, SB1;

    auto T_of = [&](int s) { return dirB ? (127 - s) : (2 + s); };

    auto issue = [&](float4& X0, float4& X1, int t) {
        const float* p = scores + ((size_t)t * BATCH + b) * TTT;
        X0 = *(const float4*)(p + offA);
        X1 = *(const float4*)(p + offA + 16 * TT);
    };

    auto addr_of = [&](int o) -> int {
        return dirB ? ((o >> 2) * 32 + 4 * g + (o & 3))
                    : ((o & 31) * 32 + 4 * g + (o >> 5));
    };

    auto step = [&](float4& X0, float4& X1, int t) {
        const bool act   = (lmask[t] != 0);
        const int srcpar = dirB ? ((t + 1) & 1) : ((t - 1) & 1);
        const int tagw   = dirB ? (t + 1) : (t - 1);

        if (!dirB && act) {
            // scatter tile -> transposed LDS: smem[(f*4+q)*33 + i]
            #pragma unroll
            for (int q = 0; q < 4; ++q) smem[(f*4 + q)*33 + i0]        = (&X0.x)[q];
            #pragma unroll
            for (int q = 0; q < 4; ++q) smem[(f*4 + q)*33 + (i0 + 16)] = (&X1.x)[q];
        }

        if (tid < 64) {
            if (act) {
                const u64* src = pt + (size_t)srcpar * 1024 + 128 * g;
                u64 wv0 = 0, wv1 = 0; bool d0 = false, d1 = false;
                while (true) {
                    if (!d0) { wv0 = ald64(src + lane);      d0 = (pt_tag(wv0) == tagw); }
                    if (!d1) { wv1 = ald64(src + 64 + lane); d1 = (pt_tag(wv1) == tagw); }
                    if (__all(d0 && d1)) break;
                }
                pld[lane]      = pt_val(wv0);
                pld[lane + 64] = pt_val(wv1);
            } else {
                // masked: re-read own publish set (tag t-1/t+1) for pass-through
                const u64* base = pt + (size_t)srcpar * 1024;
                const int o0 = lane, o1 = lane + 64;
                const int a0 = addr_of(o0), a1 = addr_of(o1);
                u64 x0 = 0, x1 = 0; bool d0 = false, d1 = false;
                while (true) {
                    if (!d0) { x0 = ald64(base + a0); d0 = (pt_tag(x0) == tagw); }
                    if (!d1) { x1 = ald64(base + a1); d1 = (pt_tag(x1) == tagw); }
                    if (__all(d0 && d1)) break;
                }
                pld[o0] = pt_val(x0);
                pld[o1] = pt_val(x1);
            }
        }
        BLOCK_SYNC();   // B1: pld (and smem) ready

        if (act) {
            if (!dirB) {
                float acc = 0.f;
                #pragma unroll
                for (int m = 0; m < 8; ++m) {
                    const int i = s4*8 + m;
                    float E = exp2f(fmaf(smem[oF*33 + i], LOG2E, -OFF4));
                    acc = fmaf(E, pld[jjF*32 + i], acc);
                }
                acc += __shfl_xor(acc, 1, 64);
                acc += __shfl_xor(acc, 2, 64);
                if (s4 == 0) res[oF] = acc;
            } else {
                const float4 Rv = *(const float4*)&pld[jjB*32 + k4*4];
                float acc0, acc1;
                {
                    float e0 = exp2f(fmaf(X0.x, LOG2E, -OFF4));
                    float e1 = exp2f(fmaf(X0.y, LOG2E, -OFF4));
                    float e2 = exp2f(fmaf(X0.z, LOG2E, -OFF4));
                    float e3 = exp2f(fmaf(X0.w, LOG2E, -OFF4));
                    acc0 = fmaf(e3, Rv.w, fmaf(e2, Rv.z, fmaf(e1, Rv.y, e0 * Rv.x)));
                }
                {
                    float e0 = exp2f(fmaf(X1.x, LOG2E, -OFF4));
                    float e1 = exp2f(fmaf(X1.y, LOG2E, -OFF4));
                    float e2 = exp2f(fmaf(X1.z, LOG2E, -OFF4));
                    float e3 = exp2f(fmaf(X1.w, LOG2E, -OFF4));
                    acc1 = fmaf(e3, Rv.w, fmaf(e2, Rv.z, fmaf(e1, Rv.y, e0 * Rv.x)));
                }
                acc0 += __shfl_xor(acc0, 1, 64);
                acc0 += __shfl_xor(acc0, 2, 64);
                acc0 += __shfl_xor(acc0, 4, 64);
                acc1 += __shfl_xor(acc1, 1, 64);
                acc1 += __shfl_xor(acc1, 2, 64);
                acc1 += __shfl_xor(acc1, 4, 64);
                if (k4 == 0) {
                    res[i0*4 + jjB]        = acc0;
                    res[(i0 + 16)*4 + jjB] = acc1;
                }
            }
        }
        BLOCK_SYNC();   // B2: res ready

        if (tid < 64) {
            const int o0 = lane, o1 = lane + 64;
            const float v0 = act ? res[o0] : pld[o0];
            const float v1 = act ? res[o1] : pld[o1];
            u64* dst = pt + (size_t)(t & 1) * 1024;
            ast64(dst + addr_of(o0), pt_pack(t, v0));
            ast64(dst + addr_of(o1), pt_pack(t, v1));
        }
    };

    issue(SA0, SA1, T_of(0));
    for (int s = 0; s < 63; s += 2) {
        if (s + 1 < 63) issue(SB0, SB1, T_of(s + 1));
        step(SA0, SA1, T_of(s));
        if (s + 1 < 63) {
            if (s + 2 < 63) issue(SA0, SA1, T_of(s + 2));
            step(SB0, SB1, T_of(s + 1));
        }
    }
}

// ---------------------------------------------------------------------------
// Kernel 4: finalize. z_b = 4*cnt_b + log( sum Q_64 o R_64 ).
// Q_64: ptF parity0 layout [k*32+j]; R_64: ptB parity1 layout [j*32+k].
// ---------------------------------------------------------------------------
__global__ __launch_bounds__(1024) void finalize_dfb(const float* __restrict__ ws,
                                                     const u64*  __restrict__ ptF,
                                                     const u64*  __restrict__ ptB,
                                                     const int*  __restrict__ mask,
                                                     float*      __restrict__ out) {
    __shared__ float zs[32];
    const int w = threadIdx.x >> 6, lane = threadIdx.x & 63;
    for (int rep = 0; rep < 2; ++rep) {
        const int b = w + rep * 16;
        const u64* qf = ptF + (size_t)b * 2048;          // parity0
        const u64* rb = ptB + (size_t)b * 2048 + 1024;   // parity1
        float dot = 0.f;
        #pragma unroll
        for (int e = 0; e < 16; ++e) {
            const int x = lane + 64 * e;                 // x = k*32 + j
            dot += pt_val(qf[x]) * pt_val(rb[(x & 31) * 32 + (x >> 5)]);
        }
        float cnt = 0.f;
        {
            int t = 2 + lane;
            if (t < SEQ_LEN) cnt += (mask[t*BATCH + b] != 0) ? 1.f : 0.f;
            t += 64;
            if (t < SEQ_LEN) cnt += (mask[t*BATCH + b] != 0) ? 1.f : 0.f;
        }
        #pragma unroll
        for (int off = 32; off > 0; off >>= 1) {
            dot += __shfl_xor(dot, off, 64);
            cnt += __shfl_xor(cnt, off, 64);
        }
        if (lane == 0) zs[b] = 4.0f * cnt + logf(dot);
    }
    __syncthreads();
    if (threadIdx.x == 0) {
        float tg = 0.f, z = 0.f;
        #pragma unroll
        for (int i = 0; i < 16; ++i) tg += ws[i];
        #pragma unroll
        for (int i = 0; i < 32; ++i) z += zs[i];
        out[0] = (z - tg) / (float)BATCH;
    }
}

// ---------------------------------------------------------------------------
// Fallback (small ws): round-5 single-block-per-batch scan.
// ---------------------------------------------------------------------------
__global__ __launch_bounds__(1024) void scan_fast(const float* __restrict__ scores,
                                                  const int*   __restrict__ maskI,
                                                  float*       __restrict__ ws) {
    const int b    = blockIdx.x;
    const int tid  = threadIdx.x;
    const int w    = tid >> 6;
    const int lane = tid & 63;
    const int h    = lane >> 4;
    const int jp   = (lane >> 3) & 1;
    const int k4   = lane & 7;
    const int j    = w * 2 + jp;

    __shared__ float Q[2][TT];
    __shared__ int   lmask[SEQ_LEN];
    if (tid < SEQ_LEN) lmask[tid] = maskI[tid * BATCH + b];
    {
        int x = tid >> 5, y = tid & 31;
        float p1 = scores[(size_t)(0*BATCH + b)*TTT + START*TT + START*T + x];
        float s1 = scores[(size_t)(1*BATCH + b)*TTT + START*TT + x*T + y];
        Q[1][x*T + y] = __expf(p1 + s1);
    }
    __syncthreads();
    const int loff = h*8*TT + j*T + k4*4;
    float4 SA[8], SB[8];
    auto issue = [&](float4 (&S)[8], int t) {
        const float* p = scores + ((size_t)t*BATCH + b)*TTT + loff;
        #pragma unroll
        for (int m = 0; m < 8; ++m) S[m] = *(const float4*)(p + m*TT);
    };
    auto process = [&](float4 (&S)[8], int t) {
        const float* qc = Q[(t-1) & 1];
        float*       qn = Q[t & 1];
        #pragma unroll
        for (int m = 0; m < 8; ++m) {
            S[m].x = exp2f(fmaf(S[m].x, LOG2E, -OFF4));
            S[m].y = exp2f(fmaf(S[m].y, LOG2E, -OFF4));
            S[m].z = exp2f(fmaf(S[m].z, LOG2E, -OFF4));
            S[m].w = exp2f(fmaf(S[m].w, LOG2E, -OFF4));
        }
        float4 acc = make_float4(0.f, 0.f, 0.f, 0.f);
        #pragma unroll
        for (int m = 0; m < 8; ++m) {
            float q = qc[(h*8 + m)*T + j];
            acc.x = fmaf(S[m].x, q, acc.x);
            acc.y = fmaf(S[m].y, q, acc.y);
            acc.z = fmaf(S[m].z, q, acc.z);
            acc.w = fmaf(S[m].w, q, acc.w);
        }
        acc.x += __shfl_xor(acc.x, 16, 64); acc.y += __shfl_xor(acc.y, 16, 64);
        acc.z += __shfl_xor(acc.z, 16, 64); acc.w += __shfl_xor(acc.w, 16, 64);
        acc.x += __shfl_xor(acc.x, 32, 64); acc.y += __shfl_xor(acc.y, 32, 64);
        acc.z += __shfl_xor(acc.z, 32, 64); acc.w += __shfl_xor(acc.w, 32, 64);
        if (lane < 16) {
            if (lmask[t] != 0) *(float4*)&qn[j*T + k4*4] = acc;
            else               *(float4*)&qn[j*T + k4*4] = *(const float4*)&qc[j*T + k4*4];
        }
        BLOCK_SYNC();
    };
    issue(SA, 2);
    for (int t = 2; t < SEQ_LEN; t += 2) {
        issue(SB, t + 1);
        process(SA, t);
        if (t + 2 < SEQ_LEN) issue(SA, t + 2);
        process(SB, t + 1);
    }
    if (tid == 0) {
        int cnt = 0;
        for (int t = 2; t < SEQ_LEN; ++t) cnt += (lmask[t] != 0);
        ws[16 + b] = 4.0f * (float)cnt + logf(Q[1][END*T + END]);
    }
}

__global__ void finalize_simple(const float* __restrict__ ws, float* __restrict__ out) {
    if (threadIdx.x == 0) {
        float tg = 0.f, z = 0.f;
        #pragma unroll
        for (int i = 0; i < 16; ++i) tg += ws[i];
        #pragma unroll
        for (int i = 0; i < 32; ++i) z += ws[16 + i];
        out[0] = (z - tg) / (float)BATCH;
    }
}

extern "C" void kernel_launch(void* const* d_in, const int* in_sizes, int n_in,
                              void* d_out, int out_size, void* d_ws, size_t ws_size,
                              hipStream_t stream) {
    const float* scores = (const float*)d_in[0];
    const int*   target = (const int*)d_in[1];
    const int*   mask   = (const int*)d_in[2];
    float* out = (float*)d_out;
    float* ws  = (float*)d_ws;
    u64*   ptF = (u64*)((char*)d_ws + 1024);
    u64*   ptB = ptF + (size_t)BATCH * 2048;
    const size_t need = 1024 + (size_t)2 * BATCH * 2048 * sizeof(u64);   // ~1.05 MB

    tg_kernel<<<16, 256, 0, stream>>>(scores, target, mask, ws);
    if (ws_size >= need) {
        init_dfb<<<2*BATCH, 256, 0, stream>>>(scores, ptF, ptB);
        scan_dfb<<<512, 512, 0, stream>>>(scores, mask, ptF, ptB);
        finalize_dfb<<<1, 1024, 0, stream>>>(ws, ptF, ptB, mask, out);
    } else {
        scan_fast<<<BATCH, 1024, 0, stream>>>(scores, mask, ws);
        finalize_simple<<<1, 64, 0, stream>>>(ws, out);
    }
}